// Round 5
// baseline (374.484 us; speedup 1.0000x reference)
//
#include <hip/hip_runtime.h>
#include <math.h>

#define Bq 4
#define Hq 512
#define Nq 64
#define Lq 2048
#define PARAM (Hq*Nq)   // 32768
#define Kc 8            // chunks per (b,h)
#define CH 256          // chunk length = Lq/Kc

typedef float v2f __attribute__((ext_vector_type(2)));

// ---------------------------------------------------------------------------
// Phase 1: per-(h,n) parameter prep (w = exp(dt*A), a/b = +-2*Re/Im(C*dB)).
// ---------------------------------------------------------------------------
__global__ void prep_kernel(const float* __restrict__ log_dt,
                            const float* __restrict__ log_A_real,
                            const float* __restrict__ A_imag,
                            const float* __restrict__ B_re, const float* __restrict__ B_im,
                            const float* __restrict__ C_re, const float* __restrict__ C_im,
                            float* __restrict__ wr_, float* __restrict__ wi_,
                            float* __restrict__ a0, float* __restrict__ b0,
                            float* __restrict__ a1, float* __restrict__ b1) {
    int idx = blockIdx.x * blockDim.x + threadIdx.x;
    if (idx >= PARAM) return;
    int h = idx >> 6;
    float dt = expf(log_dt[h]);
    float Ar = -expf(log_A_real[idx]);
    float Ai = A_imag[idx];
    float er = expf(Ar * dt);
    float wr = er * cosf(Ai * dt);
    float wi = er * sinf(Ai * dt);
    wr_[idx] = wr; wi_[idx] = wi;
    float mr = wr - 1.0f, mi = wi;
    float den = Ar * Ar + Ai * Ai;
    float qr = (mr * Ar + mi * Ai) / den;
    float qi = (mi * Ar - mr * Ai) / den;
    float Br = B_re[idx], Bi = B_im[idx];
    float dBr = Br * qr - Bi * qi;
    float dBi = Br * qi + Bi * qr;
    float cr = C_re[idx], ci = C_im[idx];
    a0[idx] =  2.0f * (cr * dBr - ci * dBi);
    b0[idx] = -2.0f * (cr * dBi + ci * dBr);
    cr = C_re[PARAM + idx]; ci = C_im[PARAM + idx];
    a1[idx] =  2.0f * (cr * dBr - ci * dBi);
    b1[idx] = -2.0f * (cr * dBi + ci * dBr);
}

// ---------------------------------------------------------------------------
// Phase 1b: Wt[k][o] = W[o][k] so GEMM s_loads contiguous o.
// ---------------------------------------------------------------------------
__global__ __launch_bounds__(256)
void transpose_kernel(const float* __restrict__ W, float* __restrict__ Wt) {
    __shared__ float t[32][33];
    int bx = blockIdx.x * 32;          // k base
    int by = blockIdx.y * 32;          // o base
    int tx = threadIdx.x & 31, ty = threadIdx.x >> 5;
    #pragma unroll
    for (int r = 0; r < 4; ++r)
        t[ty + 8 * r][tx] = W[(size_t)(by + ty + 8 * r) * Hq + bx + tx];
    __syncthreads();
    #pragma unroll
    for (int r = 0; r < 4; ++r)
        Wt[(size_t)(bx + ty + 8 * r) * Hq + by + tx] = t[tx][ty + 8 * r];
}

// ---------------------------------------------------------------------------
// Phase 2a: LN partial stats. Block = 64 l-lanes x 4 h-threads; each block
// covers 128 h-rows (hs split of 4). Fully coalesced 256B row segments.
// ---------------------------------------------------------------------------
__global__ __launch_bounds__(256)
void stats1_kernel(const float* __restrict__ x, float2* __restrict__ part) {
    int lt = blockIdx.x;               // 0..31  (l tile of 64)
    int hs = blockIdx.y;               // 0..3   (h split)
    int b  = blockIdx.z;
    int l  = (threadIdx.x & 63) + lt * 64;
    int hg = threadIdx.x >> 6;         // 0..3
    const float* xb = x + (size_t)b * Hq * Lq;
    float s = 0.f, s2 = 0.f;
    #pragma unroll 4
    for (int r = 0; r < 32; ++r) {
        int h = hs * 128 + hg * 32 + r;
        float v = xb[(size_t)h * Lq + l];
        s += v; s2 += v * v;
    }
    __shared__ float sA[4][64], s2A[4][64];
    sA[hg][threadIdx.x & 63] = s; s2A[hg][threadIdx.x & 63] = s2;
    __syncthreads();
    if (threadIdx.x < 64) {
        int ll = threadIdx.x;
        float ss = sA[0][ll] + sA[1][ll] + sA[2][ll] + sA[3][ll];
        float qq = s2A[0][ll] + s2A[1][ll] + s2A[2][ll] + s2A[3][ll];
        part[((size_t)hs * Bq + b) * Lq + lt * 64 + ll] = make_float2(ss, qq);
    }
}

// ---------------------------------------------------------------------------
// Phase 2b: finalize mu / rsig per (b,l).
// ---------------------------------------------------------------------------
__global__ __launch_bounds__(256)
void stats2_kernel(const float2* __restrict__ part,
                   float* __restrict__ mu_, float* __restrict__ rs_) {
    int i = blockIdx.x * 256 + threadIdx.x;    // 0..B*L-1
    float s = 0.f, q = 0.f;
    #pragma unroll
    for (int hs = 0; hs < 4; ++hs) {
        float2 p = part[(size_t)hs * Bq * Lq + i];
        s += p.x; q += p.y;
    }
    float mu = s * (1.0f / Hq);
    float var = q * (1.0f / Hq) - mu * mu;
    mu_[i] = mu;
    rs_[i] = rsqrtf(var + 1e-5f);
}

// ---------------------------------------------------------------------------
// Phase 3A: chunk-local states from zero init. One wave per (bh, chunk).
// Packed v2f: component 0 = fwd (ascending), 1 = bwd (descending). LN applied
// on the fly in staging lanes. 4 packed VALU per t.
// ---------------------------------------------------------------------------
__global__ __launch_bounds__(64)
void scanA_kernel(const float* __restrict__ x,
                  const float* __restrict__ mu_, const float* __restrict__ rs_,
                  const float* __restrict__ lnw, const float* __restrict__ lnb,
                  const float* __restrict__ wr_, const float* __restrict__ wi_,
                  float4* __restrict__ Sout) {
    int blk = blockIdx.x;
    int bh = blk >> 3, c = blk & 7;
    int b = bh >> 9, h = bh & (Hq - 1);
    int n = threadIdx.x;
    float wr = wr_[h * Nq + n], wi = wi_[h * Nq + n];
    v2f wr2 = { wr, wr }, wi2 = { wi, wi };
    float gw = lnw[h], gb = lnb[h];
    const float* xr = x + (size_t)bh * Lq;
    const float* mur = mu_ + (size_t)b * Lq;
    const float* rsr = rs_ + (size_t)b * Lq;
    __shared__ v2f zp[16];
    int W0 = c * CH, W1e = W0 + CH - 1;
    v2f sr = {0.f, 0.f}, si = {0.f, 0.f};
    for (int q0 = 0; q0 < CH; q0 += 16) {
        if (n < 16) {
            int t = W0 + q0 + n;
            ((float*)zp)[2 * n] = (xr[t] - mur[t]) * rsr[t] * gw + gb;
        } else if (n >= 32 && n < 48) {
            int t = W1e - q0 - (n - 32);
            ((float*)zp)[2 * (n - 32) + 1] = (xr[t] - mur[t]) * rsr[t] * gw + gb;
        }
        __syncthreads();
        #pragma unroll
        for (int k = 0; k < 16; ++k) {
            v2f zt = zp[k];
            v2f t1 = __builtin_elementwise_fma(wi2, si, -zt);
            v2f t2 = wi2 * sr;
            sr = __builtin_elementwise_fma(wr2, sr, -t1);
            si = __builtin_elementwise_fma(wr2, si, t2);
        }
        __syncthreads();
    }
    Sout[(size_t)blk * 64 + n] = make_float4(sr.x, sr.y, si.x, si.y);
}

// ---------------------------------------------------------------------------
// Phase 3fix: per (bh, n): w^CH by 8 squarings, then 8-step sequential combine
// (packed fwd + mirror-mapped bwd). In-place: reads S, writes init states I
// over the same buffer. Block (bh,c) later needs {F(c).fwd, F(K-1-c).bwd}.
// ---------------------------------------------------------------------------
__global__ __launch_bounds__(64)
void fix_kernel(const float* __restrict__ wr_, const float* __restrict__ wi_,
                float4* __restrict__ SI) {
    int bh = blockIdx.x;
    int h = bh & (Hq - 1);
    int n = threadIdx.x;
    float pr = wr_[h * Nq + n], pi = wi_[h * Nq + n];
    #pragma unroll
    for (int i = 0; i < 8; ++i) {      // w^(2^8) = w^256 = w^CH
        float nr = pr * pr - pi * pi;
        float ni = 2.f * pr * pi;
        pr = nr; pi = ni;
    }
    float Sfr[Kc], Sfi[Kc], Sbr[Kc], Sbi[Kc];
    #pragma unroll
    for (int c = 0; c < Kc; ++c) {
        float4 s = SI[((size_t)bh * Kc + c) * 64 + n];
        Sfr[c] = s.x; Sbr[c] = s.y; Sfi[c] = s.z; Sbi[c] = s.w;
    }
    v2f Fr = {0.f, 0.f}, Fi = {0.f, 0.f};
    v2f FrA[Kc], FiA[Kc];
    v2f pr2 = { pr, pr }, pi2 = { pi, pi };
    #pragma unroll
    for (int c = 0; c < Kc; ++c) {
        FrA[c] = Fr; FiA[c] = Fi;
        v2f T_r = { Sfr[c], Sbr[Kc - 1 - c] };
        v2f T_i = { Sfi[c], Sbi[Kc - 1 - c] };
        v2f nr = pr2 * Fr - pi2 * Fi + T_r;
        v2f ni = pr2 * Fi + pi2 * Fr + T_i;
        Fr = nr; Fi = ni;
    }
    #pragma unroll
    for (int c = 0; c < Kc; ++c)
        SI[((size_t)bh * Kc + c) * 64 + n] =
            make_float4(FrA[c].x, FrA[Kc - 1 - c].y, FiA[c].x, FiA[Kc - 1 - c].y);
}

// ---------------------------------------------------------------------------
// Phase 3C: full windowed scan with correct init + projection + LDS transpose.
// Fwd chunk c and bwd processed-chunk K-1-c both emit outputs in window
// [c*CH,(c+1)*CH): y0/y1 stay in LDS; the one boundary element
// y1win[CH-1] = proj(r_init) via shfl butterfly. Tail fuses D-skip + gelu,
// recomputing LN(x) on the fly; writes only u.
// ---------------------------------------------------------------------------
__global__ __launch_bounds__(64)
void scanC_kernel(const float* __restrict__ x,
                  const float* __restrict__ mu_, const float* __restrict__ rs_,
                  const float* __restrict__ lnw, const float* __restrict__ lnb,
                  const float* __restrict__ wr_, const float* __restrict__ wi_,
                  const float* __restrict__ a0, const float* __restrict__ b0,
                  const float* __restrict__ a1, const float* __restrict__ b1,
                  const float* __restrict__ Dv,
                  const float4* __restrict__ I, float* __restrict__ u) {
    int blk = blockIdx.x;
    int bh = blk >> 3, c = blk & 7;
    int b = bh >> 9, h = bh & (Hq - 1);
    int n = threadIdx.x;
    int pidx = h * Nq + n;
    float wr = wr_[pidx], wi = wi_[pidx];
    v2f wr2 = { wr, wr }, wi2 = { wi, wi };
    v2f pa = { a0[pidx], a1[pidx] };
    v2f pb = { b0[pidx], b1[pidx] };
    float gw = lnw[h], gb = lnb[h];

    float4 iv = I[(size_t)blk * 64 + n];
    v2f sr = { iv.x, iv.y }, si = { iv.z, iv.w };

    __shared__ float tile_f[64][17];
    __shared__ float tile_b[64][17];
    __shared__ v2f zp[16];
    __shared__ float y0win[CH], y1win[CH];

    // boundary: y1[W1-1] = proj(r_init) summed over n
    float bnd = pa.y * sr.y + pb.y * si.y;
    #pragma unroll
    for (int off = 1; off < 64; off <<= 1) bnd += __shfl_xor(bnd, off, 64);
    if (n == 0) y1win[CH - 1] = bnd;

    const float* xr = x + (size_t)bh * Lq;
    const float* mur = mu_ + (size_t)b * Lq;
    const float* rsr = rs_ + (size_t)b * Lq;
    int W0 = c * CH, W1e = W0 + CH - 1;
    int tloc = n & 15, quad = n >> 4;

    for (int q0 = 0; q0 < CH; q0 += 16) {
        if (n < 16) {
            int t = W0 + q0 + n;
            ((float*)zp)[2 * n] = (xr[t] - mur[t]) * rsr[t] * gw + gb;
        } else if (n >= 32 && n < 48) {
            int t = W1e - q0 - (n - 32);
            ((float*)zp)[2 * (n - 32) + 1] = (xr[t] - mur[t]) * rsr[t] * gw + gb;
        }
        __syncthreads();
        #pragma unroll
        for (int k = 0; k < 16; ++k) {
            v2f zt = zp[k];
            v2f t1 = __builtin_elementwise_fma(wi2, si, -zt);
            v2f t2 = wi2 * sr;
            sr = __builtin_elementwise_fma(wr2, sr, -t1);
            si = __builtin_elementwise_fma(wr2, si, t2);
            v2f p = __builtin_elementwise_fma(pa, sr, pb * si);
            tile_f[n][k] = p.x;
            tile_b[n][k] = p.y;
        }
        __syncthreads();
        float af = 0.f, ab = 0.f;
        #pragma unroll
        for (int j = 0; j < 16; ++j) {
            af += tile_f[quad * 16 + j][tloc];
            ab += tile_b[quad * 16 + j][tloc];
        }
        af += __shfl_xor(af, 16, 64);
        af += __shfl_xor(af, 32, 64);
        ab += __shfl_xor(ab, 16, 64);
        ab += __shfl_xor(ab, 32, 64);
        if (n < 16) {
            y0win[q0 + tloc] = af;
        } else if (n < 32) {
            int idx = CH - 2 - q0 - tloc;      // bwd output, window-local
            if (idx >= 0) y1win[idx] = ab;
        }
    }
    __syncthreads();
    // ---- fused activation tail: u = gelu(y0 + y1 + D*z), z recomputed ----
    float d = Dv[h];
    float* ur = u + (size_t)bh * Lq;
    for (int t0 = n; t0 < CH; t0 += 64) {
        int t = W0 + t0;
        float zt = (xr[t] - mur[t]) * rsr[t] * gw + gb;
        float v = y0win[t0] + y1win[t0] + d * zt;
        float g = 0.7978845608028654f * (v + 0.044715f * v * v * v);
        g = fminf(fmaxf(g, -15.f), 15.f);
        float e = __expf(2.0f * g);
        float th = (e - 1.0f) * __builtin_amdgcn_rcpf(e + 1.0f);
        ur[t] = 0.5f * v * (1.0f + th);
    }
}

// ---------------------------------------------------------------------------
// Phase 5: out[b,o,l] = bias[o] + x[b,o,l] + sum_k W[o,k]*u[b,k,l]
// Scalar-broadcast GEMM (o0 from blockIdx only -> s_load W rows).
// ---------------------------------------------------------------------------
__global__ __launch_bounds__(256)
void gemm_kernel(const float* __restrict__ u, const float* __restrict__ Wt,
                 const float* __restrict__ bias, const float* __restrict__ x,
                 float* __restrict__ out) {
    int o0 = blockIdx.y * 16;                    // block-uniform (blockIdx only!)
    int b  = blockIdx.z;
    int l  = blockIdx.x * 256 + threadIdx.x;
    const float* ub = u + (size_t)b * Hq * Lq + l;

    float acc[16];
    #pragma unroll
    for (int o = 0; o < 16; ++o) acc[o] = 0.f;

    // 8-deep u prefetch ring; tail overrun (rows 512..519) lands in the
    // SI buffer placed directly after u — allocated, value unused.
    float up[8];
    #pragma unroll
    for (int i = 0; i < 8; ++i) up[i] = ub[(size_t)i * Lq];

    for (int k0 = 0; k0 < Hq; k0 += 8) {
        #pragma unroll
        for (int kk = 0; kk < 8; ++kk) {
            float uv = up[kk];
            up[kk] = ub[(size_t)(k0 + 8 + kk) * Lq];
            const float* wrow = Wt + (size_t)(k0 + kk) * Hq + o0;  // uniform
            #pragma unroll
            for (int o = 0; o < 16; ++o)
                acc[o] = fmaf(wrow[o], uv, acc[o]);
        }
    }

    #pragma unroll
    for (int o = 0; o < 16; ++o) {
        size_t idx = ((size_t)b * Hq + o0 + o) * Lq + l;
        out[idx] = acc[o] + bias[o0 + o] + x[idx];
    }
}

// ---------------------------------------------------------------------------
extern "C" void kernel_launch(void* const* d_in, const int* in_sizes, int n_in,
                              void* d_out, int out_size, void* d_ws, size_t ws_size,
                              hipStream_t stream) {
    (void)in_sizes; (void)n_in; (void)out_size; (void)ws_size;
    const float* x          = (const float*)d_in[0];
    const float* ln_w       = (const float*)d_in[1];
    const float* ln_b       = (const float*)d_in[2];
    const float* log_dt     = (const float*)d_in[3];
    const float* log_A_real = (const float*)d_in[4];
    const float* A_imag     = (const float*)d_in[5];
    const float* B_re       = (const float*)d_in[6];
    const float* B_im       = (const float*)d_in[7];
    const float* C_re       = (const float*)d_in[8];
    const float* C_im       = (const float*)d_in[9];
    const float* Dv         = (const float*)d_in[10];
    const float* W          = (const float*)d_in[11];
    const float* b_out      = (const float*)d_in[12];
    float* out = (float*)d_out;
    float* ws  = (float*)d_ws;

    float* wr   = ws;                                  // PARAM each
    float* wi   = wr + PARAM;
    float* a0   = wi + PARAM;
    float* b0   = a0 + PARAM;
    float* a1   = b0 + PARAM;
    float* b1   = a1 + PARAM;
    float* Wt   = b1 + PARAM;                          // 512*512
    float* mu   = Wt + Hq * Hq;                        // B*L
    float* rsig = mu + Bq * Lq;                        // B*L
    float* part = rsig + Bq * Lq;                      // float2[4][B*L]
    float* u    = part + 8 * Bq * Lq;                  // B*H*L
    float* SI   = u + (size_t)Bq * Hq * Lq;            // 16384*64 float4

    prep_kernel<<<PARAM / 256, 256, 0, stream>>>(log_dt, log_A_real, A_imag,
                                                 B_re, B_im, C_re, C_im,
                                                 wr, wi, a0, b0, a1, b1);
    transpose_kernel<<<dim3(Hq / 32, Hq / 32), 256, 0, stream>>>(W, Wt);
    stats1_kernel<<<dim3(Lq / 64, 4, Bq), 256, 0, stream>>>(x, (float2*)part);
    stats2_kernel<<<Bq * Lq / 256, 256, 0, stream>>>((const float2*)part, mu, rsig);
    scanA_kernel<<<Bq * Hq * Kc, 64, 0, stream>>>(x, mu, rsig, ln_w, ln_b,
                                                  wr, wi, (float4*)SI);
    fix_kernel<<<Bq * Hq, 64, 0, stream>>>(wr, wi, (float4*)SI);
    scanC_kernel<<<Bq * Hq * Kc, 64, 0, stream>>>(x, mu, rsig, ln_w, ln_b,
                                                  wr, wi, a0, b0, a1, b1, Dv,
                                                  (const float4*)SI, u);
    gemm_kernel<<<dim3(Lq / 256, Hq / 16, Bq), 256, 0, stream>>>(u, Wt, b_out, x, out);
}

// Round 6
// 360.951 us; speedup vs baseline: 1.0375x; 1.0375x over previous
//
#include <hip/hip_runtime.h>
#include <math.h>

#define Bq 4
#define Hq 512
#define Nq 64
#define Lq 2048
#define PARAM (Hq*Nq)   // 32768
#define Kc 8            // chunks per (b,h)
#define CH 256          // chunk length

typedef float v2f __attribute__((ext_vector_type(2)));

// ---------------------------------------------------------------------------
// Phase 1: per-(h,n) parameter prep (w = exp(dt*A), a/b = +-2*Re/Im(C*dB)).
// ---------------------------------------------------------------------------
__global__ void prep_kernel(const float* __restrict__ log_dt,
                            const float* __restrict__ log_A_real,
                            const float* __restrict__ A_imag,
                            const float* __restrict__ B_re, const float* __restrict__ B_im,
                            const float* __restrict__ C_re, const float* __restrict__ C_im,
                            float* __restrict__ wr_, float* __restrict__ wi_,
                            float* __restrict__ a0, float* __restrict__ b0,
                            float* __restrict__ a1, float* __restrict__ b1) {
    int idx = blockIdx.x * blockDim.x + threadIdx.x;
    if (idx >= PARAM) return;
    int h = idx >> 6;
    float dt = expf(log_dt[h]);
    float Ar = -expf(log_A_real[idx]);
    float Ai = A_imag[idx];
    float er = expf(Ar * dt);
    float wr = er * cosf(Ai * dt);
    float wi = er * sinf(Ai * dt);
    wr_[idx] = wr; wi_[idx] = wi;
    float mr = wr - 1.0f, mi = wi;
    float den = Ar * Ar + Ai * Ai;
    float qr = (mr * Ar + mi * Ai) / den;
    float qi = (mi * Ar - mr * Ai) / den;
    float Br = B_re[idx], Bi = B_im[idx];
    float dBr = Br * qr - Bi * qi;
    float dBi = Br * qi + Bi * qr;
    float cr = C_re[idx], ci = C_im[idx];
    a0[idx] =  2.0f * (cr * dBr - ci * dBi);
    b0[idx] = -2.0f * (cr * dBi + ci * dBr);
    cr = C_re[PARAM + idx]; ci = C_im[PARAM + idx];
    a1[idx] =  2.0f * (cr * dBr - ci * dBi);
    b1[idx] = -2.0f * (cr * dBi + ci * dBr);
}

// ---------------------------------------------------------------------------
// Phase 1b: Wt[k][o] = W[o][k] (contiguous-o rows for GEMM staging).
// ---------------------------------------------------------------------------
__global__ __launch_bounds__(256)
void transpose_kernel(const float* __restrict__ W, float* __restrict__ Wt) {
    __shared__ float t[32][33];
    int bx = blockIdx.x * 32;          // k base
    int by = blockIdx.y * 32;          // o base
    int tx = threadIdx.x & 31, ty = threadIdx.x >> 5;
    #pragma unroll
    for (int r = 0; r < 4; ++r)
        t[ty + 8 * r][tx] = W[(size_t)(by + ty + 8 * r) * Hq + bx + tx];
    __syncthreads();
    #pragma unroll
    for (int r = 0; r < 4; ++r)
        Wt[(size_t)(bx + ty + 8 * r) * Hq + by + tx] = t[tx][ty + 8 * r];
}

// ---------------------------------------------------------------------------
// Phase 2: LayerNorm over H per (b,l), writes z. 512 blocks, 16l x 16h.
// ---------------------------------------------------------------------------
__global__ __launch_bounds__(256)
void ln_kernel(const float* __restrict__ x, const float* __restrict__ lnw,
               const float* __restrict__ lnb, float* __restrict__ z) {
    int blk = blockIdx.x;
    int b  = blk / (Lq / 16);
    int l0 = (blk % (Lq / 16)) * 16;
    int tx = threadIdx.x & 15;
    int ty = threadIdx.x >> 4;
    const float* xb = x + (size_t)b * Hq * Lq;
    float s = 0.f, s2 = 0.f;
    for (int h = ty; h < Hq; h += 16) {
        float v = xb[h * Lq + l0 + tx];
        s += v; s2 += v * v;
    }
    __shared__ float rs_[16][17], r2_[16][17], mu_s[16], sg_s[16];
    rs_[ty][tx] = s; r2_[ty][tx] = s2;
    __syncthreads();
    if (ty == 0) {
        float a = 0.f, c = 0.f;
        #pragma unroll
        for (int i = 0; i < 16; ++i) { a += rs_[i][tx]; c += r2_[i][tx]; }
        float mu = a * (1.0f / Hq);
        float var = c * (1.0f / Hq) - mu * mu;
        mu_s[tx] = mu;
        sg_s[tx] = rsqrtf(var + 1e-5f);
    }
    __syncthreads();
    float mu = mu_s[tx], rs = sg_s[tx];
    float* zb = z + (size_t)b * Hq * Lq;
    for (int h = ty; h < Hq; h += 16) {
        float v = xb[h * Lq + l0 + tx];
        zb[h * Lq + l0 + tx] = (v - mu) * rs * lnw[h] + lnb[h];
    }
}

// ---------------------------------------------------------------------------
// Phase 3A: chunk-local final states, zero init. One wave per (bh,c).
// z via double-buffered SCALAR loads (address = blockIdx + loop counter only
// -> s_load_dwordx8; round-3 lesson: any threadIdx taint kills this).
// No LDS, no barriers: pure 4-pk-VALU recurrence per t.
// NOTE: prefetch over/underruns by 8 floats land in adjacent ws buffers
// (Wt before z, SI after z) — allocated, values unused.
// ---------------------------------------------------------------------------
__global__ __launch_bounds__(64)
void scanA_kernel(const float* __restrict__ z,
                  const float* __restrict__ wr_, const float* __restrict__ wi_,
                  float4* __restrict__ Sout) {
    int blk = blockIdx.x;              // (bh, c)
    int bh = blk >> 3, c = blk & 7;
    int h = bh & (Hq - 1);
    int n = threadIdx.x;
    float wr = wr_[h * Nq + n], wi = wi_[h * Nq + n];
    v2f wr2 = { wr, wr }, wi2 = { wi, wi };
    const float* zz = z + (size_t)bh * Lq + c * CH;
    v2f sr = {0.f, 0.f}, si = {0.f, 0.f};
    float zf0[8], zb0[8], zf1[8], zb1[8];
    #pragma unroll
    for (int i = 0; i < 8; ++i) { zf0[i] = zz[i]; zb0[i] = zz[CH - 8 + i]; }
    for (int q0 = 0; q0 < CH; q0 += 16) {
        #pragma unroll
        for (int i = 0; i < 8; ++i) {
            zf1[i] = zz[q0 + 8 + i];
            zb1[i] = zz[CH - 16 - q0 + i];
        }
        #pragma unroll
        for (int k = 0; k < 8; ++k) {
            v2f zt = { zf0[k], zb0[7 - k] };
            v2f t1 = __builtin_elementwise_fma(wi2, si, -zt);
            v2f t2 = wi2 * sr;
            sr = __builtin_elementwise_fma(wr2, sr, -t1);
            si = __builtin_elementwise_fma(wr2, si, t2);
        }
        #pragma unroll
        for (int i = 0; i < 8; ++i) {
            zf0[i] = zz[q0 + 16 + i];        // dead on last iter (safe region)
            zb0[i] = zz[CH - 24 - q0 + i];   // dead on last iter (safe region)
        }
        #pragma unroll
        for (int k = 0; k < 8; ++k) {
            v2f zt = { zf1[k], zb1[7 - k] };
            v2f t1 = __builtin_elementwise_fma(wi2, si, -zt);
            v2f t2 = wi2 * sr;
            sr = __builtin_elementwise_fma(wr2, sr, -t1);
            si = __builtin_elementwise_fma(wr2, si, t2);
        }
    }
    Sout[(size_t)blk * 64 + n] = make_float4(sr.x, sr.y, si.x, si.y);
}

// ---------------------------------------------------------------------------
// Phase 3fix: per (bh,n): w^CH via squarings + 8-step packed combine.
// In-place S -> per-chunk init states (fwd c pairs with bwd K-1-c).
// ---------------------------------------------------------------------------
__global__ __launch_bounds__(64)
void fix_kernel(const float* __restrict__ wr_, const float* __restrict__ wi_,
                float4* __restrict__ SI) {
    int bh = blockIdx.x;
    int h = bh & (Hq - 1);
    int n = threadIdx.x;
    float pr = wr_[h * Nq + n], pi = wi_[h * Nq + n];
    #pragma unroll
    for (int i = 0; i < 8; ++i) {      // w^(2^8) = w^256
        float nr = pr * pr - pi * pi;
        float ni = 2.f * pr * pi;
        pr = nr; pi = ni;
    }
    float Sfr[Kc], Sfi[Kc], Sbr[Kc], Sbi[Kc];
    #pragma unroll
    for (int c = 0; c < Kc; ++c) {
        float4 s = SI[((size_t)bh * Kc + c) * 64 + n];
        Sfr[c] = s.x; Sbr[c] = s.y; Sfi[c] = s.z; Sbi[c] = s.w;
    }
    v2f Fr = {0.f, 0.f}, Fi = {0.f, 0.f};
    v2f FrA[Kc], FiA[Kc];
    v2f pr2 = { pr, pr }, pi2 = { pi, pi };
    #pragma unroll
    for (int c = 0; c < Kc; ++c) {
        FrA[c] = Fr; FiA[c] = Fi;
        v2f T_r = { Sfr[c], Sbr[Kc - 1 - c] };
        v2f T_i = { Sfi[c], Sbi[Kc - 1 - c] };
        v2f nr = pr2 * Fr - pi2 * Fi + T_r;
        v2f ni = pr2 * Fi + pi2 * Fr + T_i;
        Fr = nr; Fi = ni;
    }
    #pragma unroll
    for (int c = 0; c < Kc; ++c)
        SI[((size_t)bh * Kc + c) * 64 + n] =
            make_float4(FrA[c].x, FrA[Kc - 1 - c].y, FiA[c].x, FiA[Kc - 1 - c].y);
}

// ---------------------------------------------------------------------------
// Phase 3C: windowed scan with init + projection + LDS transpose + fused
// gelu tail. z via scalar double-buffered loads (no VMEM in barrier path).
// 8-t tiles: tile[64][9] 2-way-free layouts, LDS 6.7KB -> ~23 blocks/CU.
// ---------------------------------------------------------------------------
__global__ __launch_bounds__(64)
void scanC_kernel(const float* __restrict__ z,
                  const float* __restrict__ wr_, const float* __restrict__ wi_,
                  const float* __restrict__ a0, const float* __restrict__ b0,
                  const float* __restrict__ a1, const float* __restrict__ b1,
                  const float* __restrict__ Dv,
                  const float4* __restrict__ I, float* __restrict__ u) {
    int blk = blockIdx.x;
    int bh = blk >> 3, c = blk & 7;
    int h = bh & (Hq - 1);
    int n = threadIdx.x;
    int pidx = h * Nq + n;
    float wr = wr_[pidx], wi = wi_[pidx];
    v2f wr2 = { wr, wr }, wi2 = { wi, wi };
    v2f pa = { a0[pidx], a1[pidx] };
    v2f pb = { b0[pidx], b1[pidx] };

    float4 iv = I[(size_t)blk * 64 + n];
    v2f sr = { iv.x, iv.y }, si = { iv.z, iv.w };

    __shared__ float tile_f[64][9];    // write 9n+k: 2-way; read 9(8g+j)+t8: 2-way
    __shared__ float tile_b[64][9];
    __shared__ float y0win[CH], y1win[CH];

    // boundary: y1[window end] = proj(r_init), full-wave butterfly
    float bnd = pa.y * sr.y + pb.y * si.y;
    #pragma unroll
    for (int off = 1; off < 64; off <<= 1) bnd += __shfl_xor(bnd, off, 64);
    if (n == 0) y1win[CH - 1] = bnd;

    const float* zz = z + (size_t)bh * Lq + c * CH;
    int t8 = n >> 3, g = n & 7;

    float zf0[8], zb0[8], zf1[8], zb1[8];
    #pragma unroll
    for (int i = 0; i < 8; ++i) { zf0[i] = zz[i]; zb0[i] = zz[CH - 8 + i]; }

    for (int q0 = 0; q0 < CH; q0 += 16) {
        #pragma unroll
        for (int i = 0; i < 8; ++i) {
            zf1[i] = zz[q0 + 8 + i];
            zb1[i] = zz[CH - 16 - q0 + i];
        }
        // ---- tile 1 (steps q0 .. q0+7) ----
        #pragma unroll
        for (int k = 0; k < 8; ++k) {
            v2f zt = { zf0[k], zb0[7 - k] };
            v2f t1 = __builtin_elementwise_fma(wi2, si, -zt);
            v2f t2 = wi2 * sr;
            sr = __builtin_elementwise_fma(wr2, sr, -t1);
            si = __builtin_elementwise_fma(wr2, si, t2);
            v2f p = __builtin_elementwise_fma(pa, sr, pb * si);
            tile_f[n][k] = p.x;
            tile_b[n][k] = p.y;
        }
        __syncthreads();
        {
            float af = 0.f, ab = 0.f;
            #pragma unroll
            for (int j = 0; j < 8; ++j) {
                af += tile_f[g * 8 + j][t8];
                ab += tile_b[g * 8 + j][t8];
            }
            af += __shfl_xor(af, 1, 64); af += __shfl_xor(af, 2, 64); af += __shfl_xor(af, 4, 64);
            ab += __shfl_xor(ab, 1, 64); ab += __shfl_xor(ab, 2, 64); ab += __shfl_xor(ab, 4, 64);
            if (g == 0) y0win[q0 + t8] = af;
            else if (g == 1) {
                int idx = CH - 2 - q0 - t8;
                if (idx >= 0) y1win[idx] = ab;
            }
        }
        __syncthreads();
        #pragma unroll
        for (int i = 0; i < 8; ++i) {
            zf0[i] = zz[q0 + 16 + i];        // dead on last iter (safe region)
            zb0[i] = zz[CH - 24 - q0 + i];
        }
        // ---- tile 2 (steps q0+8 .. q0+15) ----
        #pragma unroll
        for (int k = 0; k < 8; ++k) {
            v2f zt = { zf1[k], zb1[7 - k] };
            v2f t1 = __builtin_elementwise_fma(wi2, si, -zt);
            v2f t2 = wi2 * sr;
            sr = __builtin_elementwise_fma(wr2, sr, -t1);
            si = __builtin_elementwise_fma(wr2, si, t2);
            v2f p = __builtin_elementwise_fma(pa, sr, pb * si);
            tile_f[n][k] = p.x;
            tile_b[n][k] = p.y;
        }
        __syncthreads();
        {
            int q1 = q0 + 8;
            float af = 0.f, ab = 0.f;
            #pragma unroll
            for (int j = 0; j < 8; ++j) {
                af += tile_f[g * 8 + j][t8];
                ab += tile_b[g * 8 + j][t8];
            }
            af += __shfl_xor(af, 1, 64); af += __shfl_xor(af, 2, 64); af += __shfl_xor(af, 4, 64);
            ab += __shfl_xor(ab, 1, 64); ab += __shfl_xor(ab, 2, 64); ab += __shfl_xor(ab, 4, 64);
            if (g == 0) y0win[q1 + t8] = af;
            else if (g == 1) {
                int idx = CH - 2 - q1 - t8;
                if (idx >= 0) y1win[idx] = ab;
            }
        }
        __syncthreads();
    }
    // ---- fused activation tail: u = gelu(y0 + y1 + D*z) ----
    float d = Dv[h];
    float* ur = u + (size_t)bh * Lq + c * CH;
    #pragma unroll
    for (int i = 0; i < 4; ++i) {
        int t0 = n + 64 * i;
        float v = y0win[t0] + y1win[t0] + d * zz[t0];
        float gg = 0.7978845608028654f * (v + 0.044715f * v * v * v);
        gg = fminf(fmaxf(gg, -15.f), 15.f);
        float e = __expf(2.0f * gg);
        float th = (e - 1.0f) * __builtin_amdgcn_rcpf(e + 1.0f);
        ur[t0] = 0.5f * v * (1.0f + th);
    }
}

// ---------------------------------------------------------------------------
// Phase 5: out[b,o,l] = bias[o] + x[b,o,l] + sum_k Wt[k][o]*u[b,k,l]
// LDS-tiled fp32 GEMM (no scalarization gamble): 64o x 128l block tile,
// 256 thr, 4o x 8l microtile, b128 LDS reads. Grid (16,8,4)=512 blocks.
// ---------------------------------------------------------------------------
__global__ __launch_bounds__(256)
void gemm_kernel(const float* __restrict__ u, const float* __restrict__ Wt,
                 const float* __restrict__ bias, const float* __restrict__ x,
                 float* __restrict__ out) {
    int l0 = blockIdx.x * 128;
    int o0 = blockIdx.y * 64;
    int b  = blockIdx.z;
    int tid = threadIdx.x;
    __shared__ float Ws[16][68];    // [k][o]
    __shared__ float Us[16][132];   // [k][l]
    const float* ub = u + (size_t)b * Hq * Lq;
    float acc[4][8] = {};
    int os = tid >> 4;              // 0..15 -> o = o0 + os*4
    int ls = tid & 15;              // l = l0 + ls*8
    int sj = tid >> 4;              // staging row
    int sc = tid & 15;

    for (int k0 = 0; k0 < Hq; k0 += 16) {
        {
            float4 wv = *(const float4*)(Wt + (size_t)(k0 + sj) * Hq + o0 + sc * 4);
            *(float4*)&Ws[sj][sc * 4] = wv;
            const float* ur = ub + (size_t)(k0 + sj) * Lq + l0 + sc * 8;
            float4 u0 = *(const float4*)ur;
            float4 u1 = *(const float4*)(ur + 4);
            *(float4*)&Us[sj][sc * 8] = u0;
            *(float4*)&Us[sj][sc * 8 + 4] = u1;
        }
        __syncthreads();
        #pragma unroll
        for (int j = 0; j < 16; ++j) {
            float4 av  = *(const float4*)&Ws[j][os * 4];
            float4 bv0 = *(const float4*)&Us[j][ls * 8];
            float4 bv1 = *(const float4*)&Us[j][ls * 8 + 4];
            const float* avp = (const float*)&av;
            const float* bvp0 = (const float*)&bv0;
            const float* bvp1 = (const float*)&bv1;
            #pragma unroll
            for (int io = 0; io < 4; ++io) {
                #pragma unroll
                for (int il = 0; il < 4; ++il) {
                    acc[io][il]     = fmaf(avp[io], bvp0[il], acc[io][il]);
                    acc[io][il + 4] = fmaf(avp[io], bvp1[il], acc[io][il + 4]);
                }
            }
        }
        __syncthreads();
    }
    #pragma unroll
    for (int io = 0; io < 4; ++io) {
        int o = o0 + os * 4 + io;
        float bo = bias[o];
        size_t base = ((size_t)b * Hq + o) * Lq + l0 + ls * 8;
        float4 x0 = *(const float4*)(x + base);
        float4 x1 = *(const float4*)(x + base + 4);
        float4 r0, r1;
        r0.x = acc[io][0] + bo + x0.x; r0.y = acc[io][1] + bo + x0.y;
        r0.z = acc[io][2] + bo + x0.z; r0.w = acc[io][3] + bo + x0.w;
        r1.x = acc[io][4] + bo + x1.x; r1.y = acc[io][5] + bo + x1.y;
        r1.z = acc[io][6] + bo + x1.z; r1.w = acc[io][7] + bo + x1.w;
        *(float4*)(out + base) = r0;
        *(float4*)(out + base + 4) = r1;
    }
}

// ---------------------------------------------------------------------------
extern "C" void kernel_launch(void* const* d_in, const int* in_sizes, int n_in,
                              void* d_out, int out_size, void* d_ws, size_t ws_size,
                              hipStream_t stream) {
    (void)in_sizes; (void)n_in; (void)out_size; (void)ws_size;
    const float* x          = (const float*)d_in[0];
    const float* ln_w       = (const float*)d_in[1];
    const float* ln_b       = (const float*)d_in[2];
    const float* log_dt     = (const float*)d_in[3];
    const float* log_A_real = (const float*)d_in[4];
    const float* A_imag     = (const float*)d_in[5];
    const float* B_re       = (const float*)d_in[6];
    const float* B_im       = (const float*)d_in[7];
    const float* C_re       = (const float*)d_in[8];
    const float* C_im       = (const float*)d_in[9];
    const float* Dv         = (const float*)d_in[10];
    const float* W          = (const float*)d_in[11];
    const float* b_out      = (const float*)d_in[12];
    float* out = (float*)d_out;
    float* ws  = (float*)d_ws;

    float* wr = ws;                                    // PARAM each
    float* wi = wr + PARAM;
    float* a0 = wi + PARAM;
    float* b0 = a0 + PARAM;
    float* a1 = b0 + PARAM;
    float* b1 = a1 + PARAM;
    float* Wt = b1 + PARAM;                            // 512*512 (pads z-underrun)
    float* z  = Wt + Hq * Hq;                          // B*H*L
    float* SI = z + (size_t)Bq * Hq * Lq;              // 16384*64 float4 (pads z-overrun)
    float* u  = SI + (size_t)Bq * Hq * Kc * 64 * 4;    // B*H*L

    prep_kernel<<<PARAM / 256, 256, 0, stream>>>(log_dt, log_A_real, A_imag,
                                                 B_re, B_im, C_re, C_im,
                                                 wr, wi, a0, b0, a1, b1);
    transpose_kernel<<<dim3(Hq / 32, Hq / 32), 256, 0, stream>>>(W, Wt);
    ln_kernel<<<Bq * (Lq / 16), 256, 0, stream>>>(x, ln_w, ln_b, z);
    scanA_kernel<<<Bq * Hq * Kc, 64, 0, stream>>>(z, wr, wi, (float4*)SI);
    fix_kernel<<<Bq * Hq, 64, 0, stream>>>(wr, wi, (float4*)SI);
    scanC_kernel<<<Bq * Hq * Kc, 64, 0, stream>>>(z, wr, wi, a0, b0, a1, b1, Dv,
                                                  (const float4*)SI, u);
    gemm_kernel<<<dim3(Lq / 128, Hq / 64, Bq), 256, 0, stream>>>(u, Wt, b_out, x, out);
}